// Round 2
// baseline (161.388 us; speedup 1.0000x reference)
//
#include <hip/hip_runtime.h>

typedef __bf16 bf16_t;
typedef __bf16 bf16x8 __attribute__((ext_vector_type(8)));
typedef float  f32x4  __attribute__((ext_vector_type(4)));

#define LDR 72  // padded LDS row stride (bf16 elems): 144 B = 9*16B, 16B aligned

__device__ __forceinline__ float bflo(unsigned u){ return __uint_as_float(u << 16); }
__device__ __forceinline__ float bfhi(unsigned u){ return __uint_as_float(u & 0xffff0000u); }

// ---------------------------------------------------------------------------
// prep: emb_bf, hw_bf = (emb @ gcn_w) in bf16, w1T/w2T = lin1/lin2 transposed bf16
// ws layout (bf16 elems): emb_bf[8192] | hw_bf[8192] | w1T[4096] | w2T[4096]
// ---------------------------------------------------------------------------
__global__ void prep_kernel(const float* __restrict__ emb,
                            const float* __restrict__ gcn_w,
                            const float* __restrict__ lin1_w,
                            const float* __restrict__ lin2_w,
                            bf16_t* __restrict__ ws)
{
    int t = blockIdx.x * 256 + threadIdx.x;     // 0..8191
    if (t >= 8192) return;
    bf16_t* emb_bf = ws;
    bf16_t* hw_bf  = ws + 8192;
    bf16_t* w1T    = ws + 16384;
    bf16_t* w2T    = ws + 20480;

    emb_bf[t] = (bf16_t)emb[t];
    int i = t >> 6, j = t & 63;
    float s = 0.f;
    #pragma unroll 8
    for (int k = 0; k < 64; ++k) s += emb[i*64 + k] * gcn_w[k*64 + j];
    hw_bf[t] = (bf16_t)s;
    if (t < 4096){
        int jj = t >> 6, kk = t & 63;           // wT[j*64+k] = w[k*64+j]
        w1T[t] = (bf16_t)lin1_w[kk*64 + jj];
        w2T[t] = (bf16_t)lin2_w[kk*64 + jj];
    }
}

// ---------------------------------------------------------------------------
// fused: one block per graph (128 nodes, 512 edges)
// MLP phases are exact VALU f32 this round (MFMA ablation); scores stay MFMA.
// ---------------------------------------------------------------------------
__global__ __launch_bounds__(256, 2) void fused_kernel(
    const int*   __restrict__ node_feature,
    const int*   __restrict__ edge_index,
    const float* __restrict__ gcn_b,
    const float* __restrict__ lin1_b,
    const float* __restrict__ lin2_b,
    const float* __restrict__ ln_g,
    const float* __restrict__ ln_b,
    const float* __restrict__ ex_w1,
    const float* __restrict__ ex_b1,
    const float* __restrict__ ex_ln_g,
    const float* __restrict__ ex_ln_b,
    const float* __restrict__ ex_w2,
    const float* __restrict__ ex_b2,
    const bf16_t* __restrict__ ws,
    float* __restrict__ out)
{
    __shared__ __align__(16) bf16_t bufA[128*LDR];   // x (emb gather), residual
    __shared__ __align__(16) bf16_t bufB[128*LDR];   // h1 -> t -> v scratch
    __shared__ __align__(16) bf16_t bufC[128*LDR];   // agg -> ef
    __shared__ __align__(16) bf16_t s_w1[4096];      // lin1^T
    __shared__ __align__(16) bf16_t s_w2[4096];      // lin2^T
    __shared__ unsigned short s_edge[512];
    __shared__ unsigned char  s_adj[512];
    __shared__ int   s_cnt[128];
    __shared__ int   s_start[128];
    __shared__ int   s_cur[128];
    __shared__ float s_dinv[128];
    __shared__ int   s_nf[128];
    __shared__ float s_b[320];     // gcn_b | lin1_b | lin2_b | ln_g | ln_b
    __shared__ float s_pm[256];
    __shared__ float s_means[64];

    const int tid  = threadIdx.x;
    const int b    = blockIdx.x;
    const int wid  = tid >> 6;
    const int lane = tid & 63;
    const int l15  = lane & 15;
    const int lg   = lane >> 4;
    const long obase = (long)b * 16257;

    const bf16_t* emb_bf = ws;
    const bf16_t* hw_bf  = ws + 8192;
    const bf16_t* w1T    = ws + 16384;
    const bf16_t* w2T    = ws + 20480;

    // ---- phase 0: node ids, zero counts, biases ----
    if (tid < 128){ s_nf[tid] = node_feature[b*128 + tid]; s_cnt[tid] = 0; }
    else if (tid < 192){
        int j = tid - 128;
        s_b[j]       = gcn_b[j];
        s_b[64 + j]  = lin1_b[j];
        s_b[128 + j] = lin2_b[j];
        s_b[192 + j] = ln_g[j];
        s_b[256 + j] = ln_b[j];
    }
    __syncthreads();

    // ---- phase 1: edge count + emb/hw gathers + weight staging ----
    {
        const int2* ei = reinterpret_cast<const int2*>(edge_index) + b*512;
        #pragma unroll
        for (int e = tid; e < 512; e += 256){
            int2 sd = ei[e];
            int s = sd.x & 127, d = sd.y & 127;
            s_edge[e] = (unsigned short)((s << 8) | d);
            atomicAdd(&s_cnt[d], 1);
        }
    }
    #pragma unroll
    for (int c = tid; c < 512; c += 256){
        reinterpret_cast<uint4*>(s_w1)[c] = reinterpret_cast<const uint4*>(w1T)[c];
        reinterpret_cast<uint4*>(s_w2)[c] = reinterpret_cast<const uint4*>(w2T)[c];
    }
    #pragma unroll
    for (int c = tid; c < 1024; c += 256){
        int row = c >> 3, ch = c & 7;
        int nf = s_nf[row];
        uint4 ve = reinterpret_cast<const uint4*>(emb_bf + nf*64)[ch];
        uint4 vh = reinterpret_cast<const uint4*>(hw_bf  + nf*64)[ch];
        reinterpret_cast<uint4*>(&bufA[row*LDR])[ch] = ve;
        reinterpret_cast<uint4*>(&bufB[row*LDR])[ch] = vh;
    }
    __syncthreads();

    // ---- phase 2: dinv, exclusive scan, bucket sort of edges by dst ----
    if (tid < 128) s_dinv[tid] = rsqrtf((float)(s_cnt[tid] + 1));
    if (tid < 64){
        int a0 = s_cnt[2*tid], a1 = s_cnt[2*tid+1];
        int s = a0 + a1;
        #pragma unroll
        for (int d = 1; d < 64; d <<= 1){
            int v = __shfl_up(s, d);
            if (lane >= d) s += v;
        }
        int excl = s - (a0 + a1);
        s_start[2*tid]   = excl;      s_cur[2*tid]   = excl;
        s_start[2*tid+1] = excl + a0; s_cur[2*tid+1] = excl + a0;
    }
    __syncthreads();
    #pragma unroll
    for (int e = tid; e < 512; e += 256){
        unsigned short sd = s_edge[e];
        int s = sd >> 8, d = sd & 255;
        int pos = atomicAdd(&s_cur[d], 1);
        s_adj[pos] = (unsigned char)s;
    }
    __syncthreads();

    // ---- phase 3: GCN agg: bufC[n] = dinv[n]*(sum dinv[s]*h1[s] + dinv[n]*h1[n]) + gcn_b
    {
        const int n  = tid >> 1;
        const int f0 = (tid & 1) << 5;
        float inner[32];
        #pragma unroll
        for (int f = 0; f < 32; ++f) inner[f] = 0.f;
        const float dn = s_dinv[n];
        {   // self loop term
            const uint4* hv = reinterpret_cast<const uint4*>(&bufB[n*LDR + f0]);
            #pragma unroll
            for (int q = 0; q < 4; ++q){
                uint4 v = hv[q];
                inner[q*8+0] += dn * bflo(v.x); inner[q*8+1] += dn * bfhi(v.x);
                inner[q*8+2] += dn * bflo(v.y); inner[q*8+3] += dn * bfhi(v.y);
                inner[q*8+4] += dn * bflo(v.z); inner[q*8+5] += dn * bfhi(v.z);
                inner[q*8+6] += dn * bflo(v.w); inner[q*8+7] += dn * bfhi(v.w);
            }
        }
        const int st = s_start[n], cn = s_cnt[n];
        for (int k = 0; k < cn; ++k){
            int src = s_adj[st + k];
            float w = s_dinv[src];
            const uint4* hv = reinterpret_cast<const uint4*>(&bufB[src*LDR + f0]);
            #pragma unroll
            for (int q = 0; q < 4; ++q){
                uint4 v = hv[q];
                inner[q*8+0] += w * bflo(v.x); inner[q*8+1] += w * bfhi(v.x);
                inner[q*8+2] += w * bflo(v.y); inner[q*8+3] += w * bfhi(v.y);
                inner[q*8+4] += w * bflo(v.z); inner[q*8+5] += w * bfhi(v.z);
                inner[q*8+6] += w * bflo(v.w); inner[q*8+7] += w * bfhi(v.w);
            }
        }
        #pragma unroll
        for (int f = 0; f < 32; ++f)
            bufC[n*LDR + f0 + f] = (bf16_t)(dn * inner[f] + s_b[f0 + f]);
    }
    __syncthreads();

    // ---- phase 4 (VALU, exact): t = relu(agg @ lin1 + b1) -> bufB ----
    {
        const int n  = tid >> 1;
        const int jb = (tid & 1) << 5;
        float xr[64];
        {
            const bf16x8* xv = reinterpret_cast<const bf16x8*>(&bufC[n*LDR]);
            #pragma unroll
            for (int q = 0; q < 8; ++q){
                bf16x8 x8 = xv[q];
                #pragma unroll
                for (int e = 0; e < 8; ++e) xr[q*8+e] = (float)x8[e];
            }
        }
        for (int j = 0; j < 32; ++j){
            const bf16x8* wr = reinterpret_cast<const bf16x8*>(&s_w1[(jb + j)*64]);
            float a = s_b[64 + jb + j];
            #pragma unroll
            for (int q = 0; q < 8; ++q){
                bf16x8 w8 = wr[q];
                #pragma unroll
                for (int e = 0; e < 8; ++e) a += xr[q*8+e] * (float)w8[e];
            }
            bufB[n*LDR + jb + j] = (bf16_t)fmaxf(a, 0.f);  // bufB dead since phase 3
        }
    }
    __syncthreads();

    // ---- phase 5 (VALU, exact dots): h2 = t @ lin2 + b2; ef = LN(h2 + x) -> bufC
    {
        const int n  = tid >> 1;
        const int jb = (tid & 1) << 5;
        float tr[64];
        {
            const bf16x8* tv = reinterpret_cast<const bf16x8*>(&bufB[n*LDR]);
            #pragma unroll
            for (int q = 0; q < 8; ++q){
                bf16x8 t8 = tv[q];
                #pragma unroll
                for (int e = 0; e < 8; ++e) tr[q*8+e] = (float)t8[e];
            }
        }
        float p1 = 0.f, p2 = 0.f;
        // pass 1: compute v, stash as bf16 in bufB row (t consumed already)
        for (int j = 0; j < 32; ++j){
            const bf16x8* wr = reinterpret_cast<const bf16x8*>(&s_w2[(jb + j)*64]);
            float a = s_b[128 + jb + j];
            #pragma unroll
            for (int q = 0; q < 8; ++q){
                bf16x8 w8 = wr[q];
                #pragma unroll
                for (int e = 0; e < 8; ++e) a += tr[q*8+e] * (float)w8[e];
            }
            a += (float)bufA[n*LDR + jb + j];
            p1 += a; p2 += a*a;
            bufB[n*LDR + jb + j] = (bf16_t)a;   // same-thread stash
        }
        // combine the two half-row partials (lanes 2n, 2n+1 adjacent in wave)
        p1 += __shfl_xor(p1, 1);
        p2 += __shfl_xor(p2, 1);
        float mean = p1 * 0.015625f;
        float var  = p2 * 0.015625f - mean*mean;
        float rstd = rsqrtf(var + 1e-5f);
        for (int j = 0; j < 32; ++j){
            float v = (float)bufB[n*LDR + jb + j];
            float e = (v - mean) * rstd * s_b[192 + jb + j] + s_b[256 + jb + j];
            bufC[n*LDR + jb + j] = (bf16_t)e;
        }
    }
    __syncthreads();

    // ---- phase 6a: per-graph column means of ef ----
    {
        int col = tid & 63, q = tid >> 6;
        float s = 0.f;
        #pragma unroll 8
        for (int r = q*32; r < q*32 + 32; ++r)
            s += (float)bufC[r*LDR + col];
        s_pm[q*64 + col] = s;
    }
    __syncthreads();
    if (tid < 64)
        s_means[tid] = (s_pm[tid] + s_pm[64+tid] + s_pm[128+tid] + s_pm[192+tid]) * 0.0078125f;
    __syncthreads();

    // ---- phase 6b: exit head (wave 0 only) ----
    if (tid < 64){
        float a = ex_b1[lane];
        #pragma unroll 8
        for (int k = 0; k < 64; ++k)
            a += s_means[k] * ex_w1[k*64 + lane];
        float p1 = a, p2 = a*a;
        #pragma unroll
        for (int m = 1; m < 64; m <<= 1){ p1 += __shfl_xor(p1, m); p2 += __shfl_xor(p2, m); }
        float mean = p1 * 0.015625f;
        float var  = p2 * 0.015625f - mean*mean;
        float u = (a - mean) * rsqrtf(var + 1e-5f) * ex_ln_g[lane] + ex_ln_b[lane];
        u = fmaxf(u, 0.f);
        float prod = u * ex_w2[lane];
        #pragma unroll
        for (int m = 1; m < 64; m <<= 1) prod += __shfl_xor(prod, m);
        if (lane == 0) out[obase + 16256] = prod + ex_b2[0];
    }

    // ---- phase 7: scores = ef @ ef^T / 8 (MFMA), triu-then-tril scatter ----
    {
        bf16x8 af[2][2];
        #pragma unroll
        for (int fm = 0; fm < 2; ++fm)
            #pragma unroll
            for (int kk = 0; kk < 2; ++kk)
                af[fm][kk] = *reinterpret_cast<const bf16x8*>(
                    &bufC[(wid*32 + fm*16 + l15)*LDR + kk*32 + lg*8]);
        f32x4 acc[2][8];
        #pragma unroll
        for (int fm = 0; fm < 2; ++fm)
            #pragma unroll
            for (int fn = 0; fn < 8; ++fn)
                acc[fm][fn] = (f32x4){0.f,0.f,0.f,0.f};
        #pragma unroll
        for (int fn = 0; fn < 8; ++fn){
            #pragma unroll
            for (int kk = 0; kk < 2; ++kk){
                bf16x8 bfr = *reinterpret_cast<const bf16x8*>(
                    &bufC[(fn*16 + l15)*LDR + kk*32 + lg*8]);
                #pragma unroll
                for (int fm = 0; fm < 2; ++fm)
                    acc[fm][fn] = __builtin_amdgcn_mfma_f32_16x16x32_bf16(
                        af[fm][kk], bfr, acc[fm][fn], 0, 0, 0);
            }
        }
        float* ob = out + obase;
        #pragma unroll
        for (int fm = 0; fm < 2; ++fm){
            #pragma unroll
            for (int fn = 0; fn < 8; ++fn){
                #pragma unroll
                for (int r = 0; r < 4; ++r){
                    int i = wid*32 + fm*16 + lg*4 + r;
                    int j = fn*16 + l15;
                    if (i != j){
                        float v = acc[fm][fn][r] * 0.125f;
                        int p = (i < j) ? (i*127 - ((i*(i-1)) >> 1) + j - i - 1)
                                        : (8128 + ((i*(i-1)) >> 1) + j);
                        ob[p] = v;
                    }
                }
            }
        }
    }
}

extern "C" void kernel_launch(void* const* d_in, const int* in_sizes, int n_in,
                              void* d_out, int out_size, void* d_ws, size_t ws_size,
                              hipStream_t stream)
{
    const int*   node_feature = (const int*)  d_in[0];
    const int*   edge_index   = (const int*)  d_in[1];
    // d_in[2] = batch_ptr (uniform arange*128, unused)
    const float* emb     = (const float*)d_in[3];
    const float* gcn_w   = (const float*)d_in[4];
    const float* gcn_b   = (const float*)d_in[5];
    const float* lin1_w  = (const float*)d_in[6];
    const float* lin1_b  = (const float*)d_in[7];
    const float* lin2_w  = (const float*)d_in[8];
    const float* lin2_b  = (const float*)d_in[9];
    const float* ln_g    = (const float*)d_in[10];
    const float* ln_b    = (const float*)d_in[11];
    const float* ex_w1   = (const float*)d_in[12];
    const float* ex_b1   = (const float*)d_in[13];
    const float* ex_ln_g = (const float*)d_in[14];
    const float* ex_ln_b = (const float*)d_in[15];
    const float* ex_w2   = (const float*)d_in[16];
    const float* ex_b2   = (const float*)d_in[17];
    bf16_t* ws  = (bf16_t*)d_ws;
    float*  out = (float*)d_out;

    prep_kernel<<<32, 256, 0, stream>>>(emb, gcn_w, lin1_w, lin2_w, ws);
    fused_kernel<<<2048, 256, 0, stream>>>(node_feature, edge_index,
        gcn_b, lin1_b, lin2_b, ln_g, ln_b,
        ex_w1, ex_b1, ex_ln_g, ex_ln_b, ex_w2, ex_b2,
        ws, out);
}

// Round 4
// 79.548 us; speedup vs baseline: 2.0288x; 2.0288x over previous
//
#include <hip/hip_runtime.h>

typedef __bf16 bf16_t;
typedef __bf16 bf16x8 __attribute__((ext_vector_type(8)));
typedef float  f32x4  __attribute__((ext_vector_type(4)));

#define LDR 72  // padded LDS row stride (bf16 elems): 144 B = 9*16B, 16B aligned

__device__ __forceinline__ float bflo(unsigned u){ return __uint_as_float(u << 16); }
__device__ __forceinline__ float bfhi(unsigned u){ return __uint_as_float(u & 0xffff0000u); }

// ws layout (bf16 elems): emb_bf[8192] | hw_bf[8192] | w1T[4096] | w2T[4096] | map (64*4 ints)
#define WS_MAP_OFF 24576

// ---------------------------------------------------------------------------
// prep: emb_bf, hw_bf = (emb @ gcn_w) bf16, w1T/w2T transposed bf16,
// plus a probe MFMA that MEASURES the per-lane/per-reg C/D output mapping
// for fragments loaded exactly the way fused_kernel loads them.
// ---------------------------------------------------------------------------
__global__ void prep_kernel(const float* __restrict__ emb,
                            const float* __restrict__ gcn_w,
                            const float* __restrict__ lin1_w,
                            const float* __restrict__ lin2_w,
                            bf16_t* __restrict__ ws)
{
    int t = blockIdx.x * 256 + threadIdx.x;     // 0..8191
    bf16_t* emb_bf = ws;
    bf16_t* hw_bf  = ws + 8192;
    bf16_t* w1T    = ws + 16384;
    bf16_t* w2T    = ws + 20480;

    emb_bf[t] = (bf16_t)emb[t];
    int i = t >> 6, j = t & 63;
    float s = 0.f;
    #pragma unroll 8
    for (int k = 0; k < 64; ++k) s += emb[i*64 + k] * gcn_w[k*64 + j];
    hw_bf[t] = (bf16_t)s;
    if (t < 4096){
        int jj = t >> 6, kk = t & 63;           // wT[j*64+k] = w[k*64+j]
        w1T[t] = (bf16_t)lin1_w[kk*64 + jj];
        w2T[t] = (bf16_t)lin2_w[kk*64 + jj];
    }

    // ---- MFMA output-map probe (block 0 only) ----
    if (blockIdx.x == 0){
        __shared__ bf16_t pA[16*32];   // A[i][k]:  k==0 -> i, k==1 -> 1, else 0
        __shared__ bf16_t pB[16*32];   // BT[j][k]: k==0 -> 1, k==1 -> 128*j, else 0
        int tid = threadIdx.x;
        for (int c = tid; c < 512; c += 256){
            int r = c >> 5, k = c & 31;
            pA[c] = (bf16_t)((k == 0) ? (float)r : ((k == 1) ? 1.f : 0.f));
            pB[c] = (bf16_t)((k == 0) ? 1.f : ((k == 1) ? (float)(128*r) : 0.f));
        }
        __syncthreads();
        if (tid < 64){
            int l15 = tid & 15, lg = tid >> 4;
            bf16x8 a  = *reinterpret_cast<const bf16x8*>(&pA[l15*32 + lg*8]);
            bf16x8 bb = *reinterpret_cast<const bf16x8*>(&pB[l15*32 + lg*8]);
            f32x4 acc = (f32x4){0.f,0.f,0.f,0.f};
            acc = __builtin_amdgcn_mfma_f32_16x16x32_bf16(a, bb, acc, 0, 0, 0);
            int* map = (int*)(ws + WS_MAP_OFF);
            #pragma unroll
            for (int r = 0; r < 4; ++r){
                int iv = (int)(acc[r] + 0.5f);          // iv = i + 128*j, exact
                map[tid*4 + r] = (iv & 127) | ((iv >> 7) << 8);  // i | j<<8
            }
        }
    }
}

// ---------------------------------------------------------------------------
// fused: one block per graph (128 nodes, 512 edges)
// MFMA MLP + scores, epilogues indexed through the measured output map.
// ---------------------------------------------------------------------------
__global__ __launch_bounds__(256, 2) void fused_kernel(
    const int*   __restrict__ node_feature,
    const int*   __restrict__ edge_index,
    const float* __restrict__ gcn_b,
    const float* __restrict__ lin1_b,
    const float* __restrict__ lin2_b,
    const float* __restrict__ ln_g,
    const float* __restrict__ ln_b,
    const float* __restrict__ ex_w1,
    const float* __restrict__ ex_b1,
    const float* __restrict__ ex_ln_g,
    const float* __restrict__ ex_ln_b,
    const float* __restrict__ ex_w2,
    const float* __restrict__ ex_b2,
    const bf16_t* __restrict__ ws,
    float* __restrict__ out)
{
    __shared__ __align__(16) bf16_t bufA[128*LDR];   // x (emb gather), residual
    __shared__ __align__(16) bf16_t bufB[128*LDR];   // h1 -> t
    __shared__ __align__(16) bf16_t bufC[128*LDR];   // agg -> v -> ef
    __shared__ __align__(16) bf16_t s_w1[4096];      // lin1^T
    __shared__ __align__(16) bf16_t s_w2[4096];      // lin2^T
    __shared__ unsigned short s_edge[512];
    __shared__ unsigned char  s_adj[512];
    __shared__ int   s_cnt[128];
    __shared__ int   s_start[128];
    __shared__ int   s_cur[128];
    __shared__ float s_dinv[128];
    __shared__ int   s_nf[128];
    __shared__ float s_b[320];     // gcn_b | lin1_b | lin2_b | ln_g | ln_b
    __shared__ float s_pm[256];
    __shared__ float s_means[64];

    const int tid  = threadIdx.x;
    const int b    = blockIdx.x;
    const int wid  = tid >> 6;
    const int lane = tid & 63;
    const int l15  = lane & 15;
    const int lg   = lane >> 4;
    const long obase = (long)b * 16257;

    const bf16_t* emb_bf = ws;
    const bf16_t* hw_bf  = ws + 8192;

    // measured output map: for acc reg r, mi[r]=row, mj[r]=col within 16x16 tile
    int mi[4], mj[4];
    {
        const int* map = (const int*)(ws + WS_MAP_OFF);
        #pragma unroll
        for (int r = 0; r < 4; ++r){
            int m = map[lane*4 + r];
            mi[r] = m & 255; mj[r] = m >> 8;
        }
    }

    // ---- phase 0: node ids, zero counts, biases ----
    if (tid < 128){ s_nf[tid] = node_feature[b*128 + tid]; s_cnt[tid] = 0; }
    else if (tid < 192){
        int j = tid - 128;
        s_b[j]       = gcn_b[j];
        s_b[64 + j]  = lin1_b[j];
        s_b[128 + j] = lin2_b[j];
        s_b[192 + j] = ln_g[j];
        s_b[256 + j] = ln_b[j];
    }
    __syncthreads();

    // ---- phase 1: edge count + emb/hw gathers + weight staging ----
    {
        const int2* ei = reinterpret_cast<const int2*>(edge_index) + b*512;
        #pragma unroll
        for (int e = tid; e < 512; e += 256){
            int2 sd = ei[e];
            int s = sd.x & 127, d = sd.y & 127;
            s_edge[e] = (unsigned short)((s << 8) | d);
            atomicAdd(&s_cnt[d], 1);
        }
    }
    #pragma unroll
    for (int c = tid; c < 512; c += 256){
        reinterpret_cast<uint4*>(s_w1)[c] = reinterpret_cast<const uint4*>(ws + 16384)[c];
        reinterpret_cast<uint4*>(s_w2)[c] = reinterpret_cast<const uint4*>(ws + 20480)[c];
    }
    #pragma unroll
    for (int c = tid; c < 1024; c += 256){
        int row = c >> 3, ch = c & 7;
        int nf = s_nf[row];
        uint4 ve = reinterpret_cast<const uint4*>(emb_bf + nf*64)[ch];
        uint4 vh = reinterpret_cast<const uint4*>(hw_bf  + nf*64)[ch];
        reinterpret_cast<uint4*>(&bufA[row*LDR])[ch] = ve;
        reinterpret_cast<uint4*>(&bufB[row*LDR])[ch] = vh;
    }
    __syncthreads();

    // ---- phase 2: dinv, exclusive scan, bucket sort of edges by dst ----
    if (tid < 128) s_dinv[tid] = rsqrtf((float)(s_cnt[tid] + 1));
    if (tid < 64){
        int a0 = s_cnt[2*tid], a1 = s_cnt[2*tid+1];
        int s = a0 + a1;
        #pragma unroll
        for (int d = 1; d < 64; d <<= 1){
            int v = __shfl_up(s, d);
            if (lane >= d) s += v;
        }
        int excl = s - (a0 + a1);
        s_start[2*tid]   = excl;      s_cur[2*tid]   = excl;
        s_start[2*tid+1] = excl + a0; s_cur[2*tid+1] = excl + a0;
    }
    __syncthreads();
    #pragma unroll
    for (int e = tid; e < 512; e += 256){
        unsigned short sd = s_edge[e];
        int s = sd >> 8, d = sd & 255;
        int pos = atomicAdd(&s_cur[d], 1);
        s_adj[pos] = (unsigned char)s;
    }
    __syncthreads();

    // ---- phase 3: GCN agg: bufC[n] = dinv[n]*(sum dinv[s]*h1[s] + dinv[n]*h1[n]) + gcn_b
    {
        const int n  = tid >> 1;
        const int f0 = (tid & 1) << 5;
        float inner[32];
        #pragma unroll
        for (int f = 0; f < 32; ++f) inner[f] = 0.f;
        const float dn = s_dinv[n];
        {   // self loop term
            const uint4* hv = reinterpret_cast<const uint4*>(&bufB[n*LDR + f0]);
            #pragma unroll
            for (int q = 0; q < 4; ++q){
                uint4 v = hv[q];
                inner[q*8+0] += dn * bflo(v.x); inner[q*8+1] += dn * bfhi(v.x);
                inner[q*8+2] += dn * bflo(v.y); inner[q*8+3] += dn * bfhi(v.y);
                inner[q*8+4] += dn * bflo(v.z); inner[q*8+5] += dn * bfhi(v.z);
                inner[q*8+6] += dn * bflo(v.w); inner[q*8+7] += dn * bfhi(v.w);
            }
        }
        const int st = s_start[n], cn = s_cnt[n];
        for (int k = 0; k < cn; ++k){
            int src = s_adj[st + k];
            float w = s_dinv[src];
            const uint4* hv = reinterpret_cast<const uint4*>(&bufB[src*LDR + f0]);
            #pragma unroll
            for (int q = 0; q < 4; ++q){
                uint4 v = hv[q];
                inner[q*8+0] += w * bflo(v.x); inner[q*8+1] += w * bfhi(v.x);
                inner[q*8+2] += w * bflo(v.y); inner[q*8+3] += w * bfhi(v.y);
                inner[q*8+4] += w * bflo(v.z); inner[q*8+5] += w * bfhi(v.z);
                inner[q*8+6] += w * bflo(v.w); inner[q*8+7] += w * bfhi(v.w);
            }
        }
        #pragma unroll
        for (int f = 0; f < 32; ++f)
            bufC[n*LDR + f0 + f] = (bf16_t)(dn * inner[f] + s_b[f0 + f]);
    }
    __syncthreads();

    // ---- phase 4 (MFMA): t = relu(agg @ lin1 + b1) -> bufB ----
    {
        bf16x8 af[2][2];
        #pragma unroll
        for (int fm = 0; fm < 2; ++fm)
            #pragma unroll
            for (int kk = 0; kk < 2; ++kk)
                af[fm][kk] = *reinterpret_cast<const bf16x8*>(
                    &bufC[(wid*32 + fm*16 + l15)*LDR + kk*32 + lg*8]);
        f32x4 acc[2][4];
        #pragma unroll
        for (int fm = 0; fm < 2; ++fm)
            #pragma unroll
            for (int fn = 0; fn < 4; ++fn)
                acc[fm][fn] = (f32x4){0.f,0.f,0.f,0.f};
        #pragma unroll
        for (int fn = 0; fn < 4; ++fn){
            #pragma unroll
            for (int kk = 0; kk < 2; ++kk){
                bf16x8 bfr = *reinterpret_cast<const bf16x8*>(
                    &s_w1[(fn*16 + l15)*64 + kk*32 + lg*8]);
                #pragma unroll
                for (int fm = 0; fm < 2; ++fm)
                    acc[fm][fn] = __builtin_amdgcn_mfma_f32_16x16x32_bf16(
                        af[fm][kk], bfr, acc[fm][fn], 0, 0, 0);
            }
        }
        #pragma unroll
        for (int fm = 0; fm < 2; ++fm)
            #pragma unroll
            for (int fn = 0; fn < 4; ++fn)
                #pragma unroll
                for (int r = 0; r < 4; ++r){
                    int row = wid*32 + fm*16 + mi[r];
                    int col = fn*16 + mj[r];
                    float v = acc[fm][fn][r] + s_b[64 + col];
                    bufB[row*LDR + col] = (bf16_t)fmaxf(v, 0.f);
                }
    }
    __syncthreads();

    // ---- phase 5 (MFMA): v = t @ lin2 + b2 + x -> bufC (raw, pre-LN) ----
    {
        bf16x8 af[2][2];
        #pragma unroll
        for (int fm = 0; fm < 2; ++fm)
            #pragma unroll
            for (int kk = 0; kk < 2; ++kk)
                af[fm][kk] = *reinterpret_cast<const bf16x8*>(
                    &bufB[(wid*32 + fm*16 + l15)*LDR + kk*32 + lg*8]);
        f32x4 acc[2][4];
        #pragma unroll
        for (int fm = 0; fm < 2; ++fm)
            #pragma unroll
            for (int fn = 0; fn < 4; ++fn)
                acc[fm][fn] = (f32x4){0.f,0.f,0.f,0.f};
        #pragma unroll
        for (int fn = 0; fn < 4; ++fn){
            #pragma unroll
            for (int kk = 0; kk < 2; ++kk){
                bf16x8 bfr = *reinterpret_cast<const bf16x8*>(
                    &s_w2[(fn*16 + l15)*64 + kk*32 + lg*8]);
                #pragma unroll
                for (int fm = 0; fm < 2; ++fm)
                    acc[fm][fn] = __builtin_amdgcn_mfma_f32_16x16x32_bf16(
                        af[fm][kk], bfr, acc[fm][fn], 0, 0, 0);
            }
        }
        #pragma unroll
        for (int fm = 0; fm < 2; ++fm)
            #pragma unroll
            for (int fn = 0; fn < 4; ++fn)
                #pragma unroll
                for (int r = 0; r < 4; ++r){
                    int row = wid*32 + fm*16 + mi[r];
                    int col = fn*16 + mj[r];
                    float v = acc[fm][fn][r] + s_b[128 + col] + (float)bufA[row*LDR + col];
                    bufC[row*LDR + col] = (bf16_t)v;
                }
    }
    __syncthreads();

    // ---- phase 5b: LN over bufC rows (map-agnostic row-owner pass) ----
    {
        const int n  = tid >> 1;
        const int f0 = (tid & 1) << 5;
        float vv[32];
        float p1 = 0.f, p2 = 0.f;
        const bf16x8* rp = reinterpret_cast<const bf16x8*>(&bufC[n*LDR + f0]);
        #pragma unroll
        for (int q = 0; q < 4; ++q){
            bf16x8 v8 = rp[q];
            #pragma unroll
            for (int e = 0; e < 8; ++e){
                float f = (float)v8[e];
                vv[q*8+e] = f; p1 += f; p2 += f*f;
            }
        }
        p1 += __shfl_xor(p1, 1);
        p2 += __shfl_xor(p2, 1);
        float mean = p1 * 0.015625f;
        float var  = p2 * 0.015625f - mean*mean;
        float rstd = rsqrtf(var + 1e-5f);
        #pragma unroll
        for (int j = 0; j < 32; ++j)
            bufC[n*LDR + f0 + j] =
                (bf16_t)((vv[j] - mean) * rstd * s_b[192 + f0 + j] + s_b[256 + f0 + j]);
    }
    __syncthreads();

    // ---- phase 6a: per-graph column means of ef ----
    {
        int col = tid & 63, q = tid >> 6;
        float s = 0.f;
        #pragma unroll 8
        for (int r = q*32; r < q*32 + 32; ++r)
            s += (float)bufC[r*LDR + col];
        s_pm[q*64 + col] = s;
    }
    __syncthreads();
    if (tid < 64)
        s_means[tid] = (s_pm[tid] + s_pm[64+tid] + s_pm[128+tid] + s_pm[192+tid]) * 0.0078125f;
    __syncthreads();

    // ---- phase 6b: exit head (wave 0 only) ----
    if (tid < 64){
        float a = ex_b1[lane];
        #pragma unroll 8
        for (int k = 0; k < 64; ++k)
            a += s_means[k] * ex_w1[k*64 + lane];
        float p1 = a, p2 = a*a;
        #pragma unroll
        for (int m = 1; m < 64; m <<= 1){ p1 += __shfl_xor(p1, m); p2 += __shfl_xor(p2, m); }
        float mean = p1 * 0.015625f;
        float var  = p2 * 0.015625f - mean*mean;
        float u = (a - mean) * rsqrtf(var + 1e-5f) * ex_ln_g[lane] + ex_ln_b[lane];
        u = fmaxf(u, 0.f);
        float prod = u * ex_w2[lane];
        #pragma unroll
        for (int m = 1; m < 64; m <<= 1) prod += __shfl_xor(prod, m);
        if (lane == 0) out[obase + 16256] = prod + ex_b2[0];
    }

    // ---- phase 7: scores = ef @ ef^T / 8 (MFMA), triu-then-tril scatter ----
    {
        bf16x8 af[2][2];
        #pragma unroll
        for (int fm = 0; fm < 2; ++fm)
            #pragma unroll
            for (int kk = 0; kk < 2; ++kk)
                af[fm][kk] = *reinterpret_cast<const bf16x8*>(
                    &bufC[(wid*32 + fm*16 + l15)*LDR + kk*32 + lg*8]);
        f32x4 acc[2][8];
        #pragma unroll
        for (int fm = 0; fm < 2; ++fm)
            #pragma unroll
            for (int fn = 0; fn < 8; ++fn)
                acc[fm][fn] = (f32x4){0.f,0.f,0.f,0.f};
        #pragma unroll
        for (int fn = 0; fn < 8; ++fn){
            #pragma unroll
            for (int kk = 0; kk < 2; ++kk){
                bf16x8 bfr = *reinterpret_cast<const bf16x8*>(
                    &bufC[(fn*16 + l15)*LDR + kk*32 + lg*8]);
                #pragma unroll
                for (int fm = 0; fm < 2; ++fm)
                    acc[fm][fn] = __builtin_amdgcn_mfma_f32_16x16x32_bf16(
                        af[fm][kk], bfr, acc[fm][fn], 0, 0, 0);
            }
        }
        float* ob = out + obase;
        #pragma unroll
        for (int fm = 0; fm < 2; ++fm){
            #pragma unroll
            for (int fn = 0; fn < 8; ++fn){
                #pragma unroll
                for (int r = 0; r < 4; ++r){
                    int i = wid*32 + fm*16 + mi[r];
                    int j = fn*16 + mj[r];
                    if (i != j){
                        float v = acc[fm][fn][r] * 0.125f;
                        int p = (i < j) ? (i*127 - ((i*(i-1)) >> 1) + j - i - 1)
                                        : (8128 + ((i*(i-1)) >> 1) + j);
                        ob[p] = v;
                    }
                }
            }
        }
    }
}

extern "C" void kernel_launch(void* const* d_in, const int* in_sizes, int n_in,
                              void* d_out, int out_size, void* d_ws, size_t ws_size,
                              hipStream_t stream)
{
    const int*   node_feature = (const int*)  d_in[0];
    const int*   edge_index   = (const int*)  d_in[1];
    // d_in[2] = batch_ptr (uniform arange*128, unused)
    const float* emb     = (const float*)d_in[3];
    const float* gcn_w   = (const float*)d_in[4];
    const float* gcn_b   = (const float*)d_in[5];
    const float* lin1_w  = (const float*)d_in[6];
    const float* lin1_b  = (const float*)d_in[7];
    const float* lin2_w  = (const float*)d_in[8];
    const float* lin2_b  = (const float*)d_in[9];
    const float* ln_g    = (const float*)d_in[10];
    const float* ln_b    = (const float*)d_in[11];
    const float* ex_w1   = (const float*)d_in[12];
    const float* ex_b1   = (const float*)d_in[13];
    const float* ex_ln_g = (const float*)d_in[14];
    const float* ex_ln_b = (const float*)d_in[15];
    const float* ex_w2   = (const float*)d_in[16];
    const float* ex_b2   = (const float*)d_in[17];
    bf16_t* ws  = (bf16_t*)d_ws;
    float*  out = (float*)d_out;

    prep_kernel<<<32, 256, 0, stream>>>(emb, gcn_w, lin1_w, lin2_w, ws);
    fused_kernel<<<2048, 256, 0, stream>>>(node_feature, edge_index,
        gcn_b, lin1_b, lin2_b, ln_g, ln_b,
        ex_w1, ex_b1, ex_ln_g, ex_ln_b, ex_w2, ex_b2,
        ws, out);
}

// Round 5
// 70.769 us; speedup vs baseline: 2.2805x; 1.1241x over previous
//
#include <hip/hip_runtime.h>

typedef __bf16 bf16_t;
typedef __bf16 bf16x8 __attribute__((ext_vector_type(8)));
typedef float  f32x4  __attribute__((ext_vector_type(4)));

#define LDR 72  // padded LDS row stride (bf16 elems): 144 B = 9*16B, 16B aligned

__device__ __forceinline__ float bflo(unsigned u){ return __uint_as_float(u << 16); }
__device__ __forceinline__ float bfhi(unsigned u){ return __uint_as_float(u & 0xffff0000u); }

// ws layout (bf16 elems): emb_bf[8192] | hw_bf[8192] | w1T[4096] | w2T[4096] | map (64*4 ints)
#define WS_MAP_OFF 24576

// ---------------------------------------------------------------------------
// prep: emb_bf, hw_bf = (emb @ gcn_w) bf16, w1T/w2T transposed bf16,
// plus a probe MFMA that MEASURES the per-lane/per-reg C/D output mapping
// for fragments loaded exactly the way fused_kernel loads them.
// ---------------------------------------------------------------------------
__global__ void prep_kernel(const float* __restrict__ emb,
                            const float* __restrict__ gcn_w,
                            const float* __restrict__ lin1_w,
                            const float* __restrict__ lin2_w,
                            bf16_t* __restrict__ ws)
{
    int t = blockIdx.x * 256 + threadIdx.x;     // 0..8191
    bf16_t* emb_bf = ws;
    bf16_t* hw_bf  = ws + 8192;
    bf16_t* w1T    = ws + 16384;
    bf16_t* w2T    = ws + 20480;

    emb_bf[t] = (bf16_t)emb[t];
    int i = t >> 6, j = t & 63;
    float s = 0.f;
    #pragma unroll 8
    for (int k = 0; k < 64; ++k) s += emb[i*64 + k] * gcn_w[k*64 + j];
    hw_bf[t] = (bf16_t)s;
    if (t < 4096){
        int jj = t >> 6, kk = t & 63;           // wT[j*64+k] = w[k*64+j]
        w1T[t] = (bf16_t)lin1_w[kk*64 + jj];
        w2T[t] = (bf16_t)lin2_w[kk*64 + jj];
    }

    // ---- MFMA output-map probe (block 0 only) ----
    if (blockIdx.x == 0){
        __shared__ bf16_t pA[16*32];   // A[i][k]:  k==0 -> i, k==1 -> 1, else 0
        __shared__ bf16_t pB[16*32];   // BT[j][k]: k==0 -> 1, k==1 -> 128*j, else 0
        int tid = threadIdx.x;
        for (int c = tid; c < 512; c += 256){
            int r = c >> 5, k = c & 31;
            pA[c] = (bf16_t)((k == 0) ? (float)r : ((k == 1) ? 1.f : 0.f));
            pB[c] = (bf16_t)((k == 0) ? 1.f : ((k == 1) ? (float)(128*r) : 0.f));
        }
        __syncthreads();
        if (tid < 64){
            int l15 = tid & 15, lg = tid >> 4;
            bf16x8 a  = *reinterpret_cast<const bf16x8*>(&pA[l15*32 + lg*8]);
            bf16x8 bb = *reinterpret_cast<const bf16x8*>(&pB[l15*32 + lg*8]);
            f32x4 acc = (f32x4){0.f,0.f,0.f,0.f};
            acc = __builtin_amdgcn_mfma_f32_16x16x32_bf16(a, bb, acc, 0, 0, 0);
            int* map = (int*)(ws + WS_MAP_OFF);
            #pragma unroll
            for (int r = 0; r < 4; ++r){
                int iv = (int)(acc[r] + 0.5f);          // iv = i + 128*j, exact
                map[tid*4 + r] = (iv & 127) | ((iv >> 7) << 8);  // i | j<<8
            }
        }
    }
}

// ---------------------------------------------------------------------------
// fused: one block per graph (128 nodes, 512 edges)
// LDS cut to ~43 KB -> 3 blocks/CU: no bufA (x re-read from global in LN
// pass), no staged weights (MFMA B-frags straight from L2-hot global).
// ---------------------------------------------------------------------------
__global__ __launch_bounds__(256, 3) void fused_kernel(
    const int*   __restrict__ node_feature,
    const int*   __restrict__ edge_index,
    const float* __restrict__ gcn_b,
    const float* __restrict__ lin1_b,
    const float* __restrict__ lin2_b,
    const float* __restrict__ ln_g,
    const float* __restrict__ ln_b,
    const float* __restrict__ ex_w1,
    const float* __restrict__ ex_b1,
    const float* __restrict__ ex_ln_g,
    const float* __restrict__ ex_ln_b,
    const float* __restrict__ ex_w2,
    const float* __restrict__ ex_b2,
    const bf16_t* __restrict__ ws,
    float* __restrict__ out)
{
    __shared__ __align__(16) bf16_t bufB[128*LDR];   // h1 -> t
    __shared__ __align__(16) bf16_t bufC[128*LDR];   // agg -> v -> ef
    __shared__ unsigned short s_edge[512];
    __shared__ unsigned char  s_adj[512];
    __shared__ int   s_cnt[128];
    __shared__ int   s_start[128];
    __shared__ int   s_cur[128];
    __shared__ float s_dinv[128];
    __shared__ int   s_nf[128];
    __shared__ float s_b[320];     // gcn_b | lin1_b | lin2_b | ln_g | ln_b
    __shared__ float s_pm[256];
    __shared__ float s_means[64];

    const int tid  = threadIdx.x;
    const int b    = blockIdx.x;
    const int wid  = tid >> 6;
    const int lane = tid & 63;
    const int l15  = lane & 15;
    const int lg   = lane >> 4;
    const long obase = (long)b * 16257;

    const bf16_t* emb_bf = ws;
    const bf16_t* hw_bf  = ws + 8192;
    const bf16_t* w1T    = ws + 16384;
    const bf16_t* w2T    = ws + 20480;

    // measured output map: for acc reg r, mi[r]=row, mj[r]=col within 16x16 tile
    int mi[4], mj[4];
    {
        const int* map = (const int*)(ws + WS_MAP_OFF);
        #pragma unroll
        for (int r = 0; r < 4; ++r){
            int m = map[lane*4 + r];
            mi[r] = m & 255; mj[r] = m >> 8;
        }
    }

    // ---- phase 0: node ids, zero counts, biases ----
    if (tid < 128){ s_nf[tid] = node_feature[b*128 + tid]; s_cnt[tid] = 0; }
    else if (tid < 192){
        int j = tid - 128;
        s_b[j]       = gcn_b[j];
        s_b[64 + j]  = lin1_b[j];
        s_b[128 + j] = lin2_b[j];
        s_b[192 + j] = ln_g[j];
        s_b[256 + j] = ln_b[j];
    }
    __syncthreads();

    // ---- phase 1: edge count + h1 gather ----
    {
        const int2* ei = reinterpret_cast<const int2*>(edge_index) + b*512;
        #pragma unroll
        for (int e = tid; e < 512; e += 256){
            int2 sd = ei[e];
            int s = sd.x & 127, d = sd.y & 127;
            s_edge[e] = (unsigned short)((s << 8) | d);
            atomicAdd(&s_cnt[d], 1);
        }
    }
    #pragma unroll
    for (int c = tid; c < 1024; c += 256){
        int row = c >> 3, ch = c & 7;
        int nf = s_nf[row];
        uint4 vh = reinterpret_cast<const uint4*>(hw_bf + nf*64)[ch];
        reinterpret_cast<uint4*>(&bufB[row*LDR])[ch] = vh;
    }
    __syncthreads();

    // ---- phase 2: dinv, exclusive scan, bucket sort of edges by dst ----
    if (tid < 128) s_dinv[tid] = rsqrtf((float)(s_cnt[tid] + 1));
    if (tid < 64){
        int a0 = s_cnt[2*tid], a1 = s_cnt[2*tid+1];
        int s = a0 + a1;
        #pragma unroll
        for (int d = 1; d < 64; d <<= 1){
            int v = __shfl_up(s, d);
            if (lane >= d) s += v;
        }
        int excl = s - (a0 + a1);
        s_start[2*tid]   = excl;      s_cur[2*tid]   = excl;
        s_start[2*tid+1] = excl + a0; s_cur[2*tid+1] = excl + a0;
    }
    __syncthreads();
    #pragma unroll
    for (int e = tid; e < 512; e += 256){
        unsigned short sd = s_edge[e];
        int s = sd >> 8, d = sd & 255;
        int pos = atomicAdd(&s_cur[d], 1);
        s_adj[pos] = (unsigned char)s;
    }
    __syncthreads();

    // ---- phase 3: GCN agg: bufC[n] = dinv[n]*(sum dinv[s]*h1[s] + dinv[n]*h1[n]) + gcn_b
    {
        const int n  = tid >> 1;
        const int f0 = (tid & 1) << 5;
        float inner[32];
        #pragma unroll
        for (int f = 0; f < 32; ++f) inner[f] = 0.f;
        const float dn = s_dinv[n];
        {   // self loop term
            const uint4* hv = reinterpret_cast<const uint4*>(&bufB[n*LDR + f0]);
            #pragma unroll
            for (int q = 0; q < 4; ++q){
                uint4 v = hv[q];
                inner[q*8+0] += dn * bflo(v.x); inner[q*8+1] += dn * bfhi(v.x);
                inner[q*8+2] += dn * bflo(v.y); inner[q*8+3] += dn * bfhi(v.y);
                inner[q*8+4] += dn * bflo(v.z); inner[q*8+5] += dn * bfhi(v.z);
                inner[q*8+6] += dn * bflo(v.w); inner[q*8+7] += dn * bfhi(v.w);
            }
        }
        const int st = s_start[n], cn = s_cnt[n];
        for (int k = 0; k < cn; ++k){
            int src = s_adj[st + k];
            float w = s_dinv[src];
            const uint4* hv = reinterpret_cast<const uint4*>(&bufB[src*LDR + f0]);
            #pragma unroll
            for (int q = 0; q < 4; ++q){
                uint4 v = hv[q];
                inner[q*8+0] += w * bflo(v.x); inner[q*8+1] += w * bfhi(v.x);
                inner[q*8+2] += w * bflo(v.y); inner[q*8+3] += w * bfhi(v.y);
                inner[q*8+4] += w * bflo(v.z); inner[q*8+5] += w * bfhi(v.z);
                inner[q*8+6] += w * bflo(v.w); inner[q*8+7] += w * bfhi(v.w);
            }
        }
        #pragma unroll
        for (int f = 0; f < 32; ++f)
            bufC[n*LDR + f0 + f] = (bf16_t)(dn * inner[f] + s_b[f0 + f]);
    }
    __syncthreads();

    // ---- phase 4 (MFMA): t = relu(agg @ lin1 + b1) -> bufB ----
    {
        bf16x8 af[2][2];
        #pragma unroll
        for (int fm = 0; fm < 2; ++fm)
            #pragma unroll
            for (int kk = 0; kk < 2; ++kk)
                af[fm][kk] = *reinterpret_cast<const bf16x8*>(
                    &bufC[(wid*32 + fm*16 + l15)*LDR + kk*32 + lg*8]);
        f32x4 acc[2][4];
        #pragma unroll
        for (int fm = 0; fm < 2; ++fm)
            #pragma unroll
            for (int fn = 0; fn < 4; ++fn)
                acc[fm][fn] = (f32x4){0.f,0.f,0.f,0.f};
        #pragma unroll
        for (int fn = 0; fn < 4; ++fn){
            #pragma unroll
            for (int kk = 0; kk < 2; ++kk){
                bf16x8 bfr = *reinterpret_cast<const bf16x8*>(
                    &w1T[(fn*16 + l15)*64 + kk*32 + lg*8]);
                #pragma unroll
                for (int fm = 0; fm < 2; ++fm)
                    acc[fm][fn] = __builtin_amdgcn_mfma_f32_16x16x32_bf16(
                        af[fm][kk], bfr, acc[fm][fn], 0, 0, 0);
            }
        }
        #pragma unroll
        for (int fm = 0; fm < 2; ++fm)
            #pragma unroll
            for (int fn = 0; fn < 4; ++fn)
                #pragma unroll
                for (int r = 0; r < 4; ++r){
                    int row = wid*32 + fm*16 + mi[r];
                    int col = fn*16 + mj[r];
                    float v = acc[fm][fn][r] + s_b[64 + col];
                    bufB[row*LDR + col] = (bf16_t)fmaxf(v, 0.f);
                }
    }
    __syncthreads();

    // ---- phase 5 (MFMA): v = t @ lin2 + b2 -> bufC (pre-residual, pre-LN) ----
    {
        bf16x8 af[2][2];
        #pragma unroll
        for (int fm = 0; fm < 2; ++fm)
            #pragma unroll
            for (int kk = 0; kk < 2; ++kk)
                af[fm][kk] = *reinterpret_cast<const bf16x8*>(
                    &bufB[(wid*32 + fm*16 + l15)*LDR + kk*32 + lg*8]);
        f32x4 acc[2][4];
        #pragma unroll
        for (int fm = 0; fm < 2; ++fm)
            #pragma unroll
            for (int fn = 0; fn < 4; ++fn)
                acc[fm][fn] = (f32x4){0.f,0.f,0.f,0.f};
        #pragma unroll
        for (int fn = 0; fn < 4; ++fn){
            #pragma unroll
            for (int kk = 0; kk < 2; ++kk){
                bf16x8 bfr = *reinterpret_cast<const bf16x8*>(
                    &w2T[(fn*16 + l15)*64 + kk*32 + lg*8]);
                #pragma unroll
                for (int fm = 0; fm < 2; ++fm)
                    acc[fm][fn] = __builtin_amdgcn_mfma_f32_16x16x32_bf16(
                        af[fm][kk], bfr, acc[fm][fn], 0, 0, 0);
            }
        }
        #pragma unroll
        for (int fm = 0; fm < 2; ++fm)
            #pragma unroll
            for (int fn = 0; fn < 4; ++fn)
                #pragma unroll
                for (int r = 0; r < 4; ++r){
                    int row = wid*32 + fm*16 + mi[r];
                    int col = fn*16 + mj[r];
                    bufC[row*LDR + col] = (bf16_t)(acc[fm][fn][r] + s_b[128 + col]);
                }
    }
    __syncthreads();

    // ---- phase 5b: ef = LN(v + x) row-owner pass; x from global emb table ----
    {
        const int n  = tid >> 1;
        const int f0 = (tid & 1) << 5;
        const bf16x8* xp = reinterpret_cast<const bf16x8*>(&emb_bf[s_nf[n]*64 + f0]);
        float vv[32];
        float p1 = 0.f, p2 = 0.f;
        const bf16x8* rp = reinterpret_cast<const bf16x8*>(&bufC[n*LDR + f0]);
        #pragma unroll
        for (int q = 0; q < 4; ++q){
            bf16x8 v8 = rp[q];
            bf16x8 x8 = xp[q];
            #pragma unroll
            for (int e = 0; e < 8; ++e){
                float f = (float)v8[e] + (float)x8[e];
                vv[q*8+e] = f; p1 += f; p2 += f*f;
            }
        }
        p1 += __shfl_xor(p1, 1);
        p2 += __shfl_xor(p2, 1);
        float mean = p1 * 0.015625f;
        float var  = p2 * 0.015625f - mean*mean;
        float rstd = rsqrtf(var + 1e-5f);
        #pragma unroll
        for (int j = 0; j < 32; ++j)
            bufC[n*LDR + f0 + j] =
                (bf16_t)((vv[j] - mean) * rstd * s_b[192 + f0 + j] + s_b[256 + f0 + j]);
    }
    __syncthreads();

    // ---- phase 6a: per-graph column means of ef ----
    {
        int col = tid & 63, q = tid >> 6;
        float s = 0.f;
        #pragma unroll 8
        for (int r = q*32; r < q*32 + 32; ++r)
            s += (float)bufC[r*LDR + col];
        s_pm[q*64 + col] = s;
    }
    __syncthreads();
    if (tid < 64)
        s_means[tid] = (s_pm[tid] + s_pm[64+tid] + s_pm[128+tid] + s_pm[192+tid]) * 0.0078125f;
    __syncthreads();

    // ---- phase 6b: exit head (wave 0 only) ----
    if (tid < 64){
        float a = ex_b1[lane];
        #pragma unroll 8
        for (int k = 0; k < 64; ++k)
            a += s_means[k] * ex_w1[k*64 + lane];
        float p1 = a, p2 = a*a;
        #pragma unroll
        for (int m = 1; m < 64; m <<= 1){ p1 += __shfl_xor(p1, m); p2 += __shfl_xor(p2, m); }
        float mean = p1 * 0.015625f;
        float var  = p2 * 0.015625f - mean*mean;
        float u = (a - mean) * rsqrtf(var + 1e-5f) * ex_ln_g[lane] + ex_ln_b[lane];
        u = fmaxf(u, 0.f);
        float prod = u * ex_w2[lane];
        #pragma unroll
        for (int m = 1; m < 64; m <<= 1) prod += __shfl_xor(prod, m);
        if (lane == 0) out[obase + 16256] = prod + ex_b2[0];
    }

    // ---- phase 7: scores = ef @ ef^T / 8 (MFMA), triu-then-tril scatter ----
    {
        bf16x8 af[2][2];
        #pragma unroll
        for (int fm = 0; fm < 2; ++fm)
            #pragma unroll
            for (int kk = 0; kk < 2; ++kk)
                af[fm][kk] = *reinterpret_cast<const bf16x8*>(
                    &bufC[(wid*32 + fm*16 + l15)*LDR + kk*32 + lg*8]);
        f32x4 acc[2][8];
        #pragma unroll
        for (int fm = 0; fm < 2; ++fm)
            #pragma unroll
            for (int fn = 0; fn < 8; ++fn)
                acc[fm][fn] = (f32x4){0.f,0.f,0.f,0.f};
        #pragma unroll
        for (int fn = 0; fn < 8; ++fn){
            #pragma unroll
            for (int kk = 0; kk < 2; ++kk){
                bf16x8 bfr = *reinterpret_cast<const bf16x8*>(
                    &bufC[(fn*16 + l15)*LDR + kk*32 + lg*8]);
                #pragma unroll
                for (int fm = 0; fm < 2; ++fm)
                    acc[fm][fn] = __builtin_amdgcn_mfma_f32_16x16x32_bf16(
                        af[fm][kk], bfr, acc[fm][fn], 0, 0, 0);
            }
        }
        float* ob = out + obase;
        #pragma unroll
        for (int fm = 0; fm < 2; ++fm){
            #pragma unroll
            for (int fn = 0; fn < 8; ++fn){
                #pragma unroll
                for (int r = 0; r < 4; ++r){
                    int i = wid*32 + fm*16 + mi[r];
                    int j = fn*16 + mj[r];
                    if (i != j){
                        float v = acc[fm][fn][r] * 0.125f;
                        int p = (i < j) ? (i*127 - ((i*(i-1)) >> 1) + j - i - 1)
                                        : (8128 + ((i*(i-1)) >> 1) + j);
                        ob[p] = v;
                    }
                }
            }
        }
    }
}

extern "C" void kernel_launch(void* const* d_in, const int* in_sizes, int n_in,
                              void* d_out, int out_size, void* d_ws, size_t ws_size,
                              hipStream_t stream)
{
    const int*   node_feature = (const int*)  d_in[0];
    const int*   edge_index   = (const int*)  d_in[1];
    // d_in[2] = batch_ptr (uniform arange*128, unused)
    const float* emb     = (const float*)d_in[3];
    const float* gcn_w   = (const float*)d_in[4];
    const float* gcn_b   = (const float*)d_in[5];
    const float* lin1_w  = (const float*)d_in[6];
    const float* lin1_b  = (const float*)d_in[7];
    const float* lin2_w  = (const float*)d_in[8];
    const float* lin2_b  = (const float*)d_in[9];
    const float* ln_g    = (const float*)d_in[10];
    const float* ln_b    = (const float*)d_in[11];
    const float* ex_w1   = (const float*)d_in[12];
    const float* ex_b1   = (const float*)d_in[13];
    const float* ex_ln_g = (const float*)d_in[14];
    const float* ex_ln_b = (const float*)d_in[15];
    const float* ex_w2   = (const float*)d_in[16];
    const float* ex_b2   = (const float*)d_in[17];
    bf16_t* ws  = (bf16_t*)d_ws;
    float*  out = (float*)d_out;

    prep_kernel<<<32, 256, 0, stream>>>(emb, gcn_w, lin1_w, lin2_w, ws);
    fused_kernel<<<2048, 256, 0, stream>>>(node_feature, edge_index,
        gcn_b, lin1_b, lin2_b, ln_g, ln_b,
        ex_w1, ex_b1, ex_ln_g, ex_ln_b, ex_w2, ex_b2,
        ws, out);
}